// Round 2
// baseline (382.719 us; speedup 1.0000x reference)
//
#include <hip/hip_runtime.h>
#include <hip/hip_fp16.h>
#include <math.h>

#define NEG_SLOPE 0.2f
#define BUCKET 96            // fixed bucket stride (slots per node); P(deg>95) ~ 1e-28

__device__ __forceinline__ float lrelu(float x) { return fmaxf(x, NEG_SLOPE * x); }

// One DPP cross-lane add step (VALU pipe, no DS ops). ctrl must be compile-time.
template <int CTRL>
__device__ __forceinline__ float dpp_add(float x) {
    int t = __builtin_amdgcn_update_dpp(0, __float_as_int(x), CTRL, 0xF, 0xF, false);
    return x + __int_as_float(t);
}

// Sum over each 8-lane group (values replicated in group).
__device__ __forceinline__ float red8(float x) {
    x = dpp_add<0xB1>(x);    // quad_perm [1,0,3,2]  (xor 1)
    x = dpp_add<0x4E>(x);    // quad_perm [2,3,0,1]  (xor 2)
    x = dpp_add<0x141>(x);   // row_half_mirror      (xor 4, quads uniform)
    return x;
}

// ---- CSR build, one pass: dst-range-partitioned direct scatter into fixed buckets.
__global__ void k_scatter(const int* __restrict__ ei, int* __restrict__ cnt,
                          int* __restrict__ ssrc, int E, int ET, int n, int nsub) {
    int part = blockIdx.x & 7;
    int sub  = blockIdx.x >> 3;
    int lo = (int)(((long long)part * n) >> 3);
    int hi = (int)(((long long)(part + 1) * n) >> 3);
    int stride = nsub * blockDim.x;
    for (int e = sub * blockDim.x + threadIdx.x; e < ET; e += stride) {
        int dst = (e < E) ? ei[E + e] : (e - E);
        if (dst >= lo && dst < hi) {
            int src = (e < E) ? ei[e] : dst;
            int pos = atomicAdd(&cnt[dst], 1);
            if (pos < BUCKET) ssrc[dst * BUCKET + pos] = src;
        }
    }
}

// ---- Layer-1 node transform: xl1 = x@W1l (fp16), xr1 = x@W1r (fp32) ----
__global__ void k_t1(const float* __restrict__ x,
                     const float* __restrict__ W1l, const float* __restrict__ W1r,
                     __half* __restrict__ xl, float* __restrict__ xr, int n) {
    __shared__ float sWl[5 * 64], sWr[5 * 64];
    int t = threadIdx.x;
    for (int i = t; i < 5 * 64; i += blockDim.x) { sWl[i] = W1l[i]; sWr[i] = W1r[i]; }
    __syncthreads();
    int tid = blockIdx.x * blockDim.x + t;
    if (tid >= n * 64) return;
    int node = tid >> 6, j = tid & 63;
    const float* xp = x + node * 5;
    float x0 = xp[0], x1 = xp[1], x2 = xp[2], x3 = xp[3], x4 = xp[4];
    float al = x0 * sWl[j] + x1 * sWl[64 + j] + x2 * sWl[128 + j] + x3 * sWl[192 + j] + x4 * sWl[256 + j];
    float ar = x0 * sWr[j] + x1 * sWr[64 + j] + x2 * sWr[128 + j] + x3 * sWr[192 + j] + x4 * sWr[256 + j];
    xl[tid] = __float2half(al);
    xr[tid] = ar;
}

// ---- Layer 1 fused GATv2 (R15 config): wave per node, 8 edges/round-slot
//      (8 groups x 8 lanes, 8 dims/lane, dwordx4 gathers), 4 batches unrolled
//      -> 32 edges per dependent round, masked tail, idx double-buffered.
//      Head logit (16 dims = lane pair) = one DPP pair-add.
//      Epilogue: h1 -> LDS -> layer-2 transform (hl fp16, hr fp32).
__global__ void __launch_bounds__(256, 5)
k_gat1(const int* __restrict__ ssrc, const int* __restrict__ deg,
       const __half* __restrict__ xl, const float* __restrict__ xr,
       const float* __restrict__ att1, const float* __restrict__ b1,
       const float* __restrict__ W2l, const float* __restrict__ W2r,
       __half* __restrict__ hl, float* __restrict__ hr, int n) {
    __shared__ float sh[4][64];
    int t = threadIdx.x;
    int wid = t >> 6, lane = t & 63;
    int node = __builtin_amdgcn_readfirstlane(blockIdx.x * 4 + wid);
    int g = lane >> 3, c = lane & 7;
    if (node < n) {
        float xrd[8], attv[8];
        {
            float4 v0 = *(const float4*)(xr + (size_t)node * 64 + 8 * c);
            float4 v1 = *(const float4*)(xr + (size_t)node * 64 + 8 * c + 4);
            xrd[0] = v0.x; xrd[1] = v0.y; xrd[2] = v0.z; xrd[3] = v0.w;
            xrd[4] = v1.x; xrd[5] = v1.y; xrd[6] = v1.z; xrd[7] = v1.w;
            float4 a0 = *(const float4*)(att1 + 8 * c);
            float4 a1 = *(const float4*)(att1 + 8 * c + 4);
            attv[0] = a0.x; attv[1] = a0.y; attv[2] = a0.z; attv[3] = a0.w;
            attv[4] = a1.x; attv[5] = a1.y; attv[6] = a1.z; attv[7] = a1.w;
        }
        float m = -1e30f, den = 0.f;
        float acc[8];
#pragma unroll
        for (int d = 0; d < 8; ++d) acc[d] = 0.f;
        const int* bp_ = ssrc + (size_t)node * BUCKET;
        int end = deg[node]; if (end > BUCKET) end = BUCKET;
        int idx[4];
#pragma unroll
        for (int j = 0; j < 4; ++j) { int e = 8 * j + g; idx[j] = bp_[e < end ? e : 0]; }
        for (int k = 0; k < end; k += 32) {
            float4 raw[4];
#pragma unroll
            for (int j = 0; j < 4; ++j)
                raw[j] = *(const float4*)((const char*)xl + (((size_t)(unsigned)idx[j]) << 7) + ((unsigned)c << 4));
            int kn = k + 32;
            if (kn < end) {
#pragma unroll
                for (int j = 0; j < 4; ++j) { int e = kn + 8 * j + g; idx[j] = bp_[e < end ? e : 0]; }
            }
            float av[4][8], s[4];
            bool vl[4];
#pragma unroll
            for (int j = 0; j < 4; ++j) {
                vl[j] = (k + 8 * j + g) < end;
                const __half2* hp = (const __half2*)&raw[j];
#pragma unroll
                for (int q = 0; q < 4; ++q) {
                    float2 f = __half22float2(hp[q]);
                    av[j][2 * q] = f.x; av[j][2 * q + 1] = f.y;
                }
                float sj = 0.f;
#pragma unroll
                for (int d = 0; d < 8; ++d) sj += lrelu(av[j][d] + xrd[d]) * attv[d];
                s[j] = dpp_add<0xB1>(sj);   // pair-sum -> per-head logit
            }
            float mb = fmaxf(fmaxf(vl[0] ? s[0] : -1e30f, vl[1] ? s[1] : -1e30f),
                             fmaxf(vl[2] ? s[2] : -1e30f, vl[3] ? s[3] : -1e30f));
            float mn = fmaxf(m, mb);
            float sc = __expf(m - mn);
            den *= sc;
#pragma unroll
            for (int d = 0; d < 8; ++d) acc[d] *= sc;
#pragma unroll
            for (int j = 0; j < 4; ++j) {
                float p = vl[j] ? __expf(s[j] - mn) : 0.f;
                den += p;
#pragma unroll
                for (int d = 0; d < 8; ++d) acc[d] += p * av[j][d];
            }
            m = mn;
        }
        // merge the 8 edge-groups (lanes with equal c share head & dims)
#pragma unroll
        for (int off = 8; off <= 32; off <<= 1) {
            float m_o = __shfl_xor(m, off, 64);
            float d_o = __shfl_xor(den, off, 64);
            float a_o[8];
#pragma unroll
            for (int d = 0; d < 8; ++d) a_o[d] = __shfl_xor(acc[d], off, 64);
            float mf = fmaxf(m, m_o);
            float s0 = __expf(m - mf), s1 = __expf(m_o - mf);
            den = den * s0 + d_o * s1;
#pragma unroll
            for (int d = 0; d < 8; ++d) acc[d] = acc[d] * s0 + a_o[d] * s1;
            m = mf;
        }
        float denf = den + 1e-16f;
        if (g == 0) {
            float4 b0 = *(const float4*)(b1 + 8 * c);
            float4 b1v = *(const float4*)(b1 + 8 * c + 4);
            float4 o0, o1;
            o0.x = fmaxf(acc[0] / denf + b0.x, 0.f);
            o0.y = fmaxf(acc[1] / denf + b0.y, 0.f);
            o0.z = fmaxf(acc[2] / denf + b0.z, 0.f);
            o0.w = fmaxf(acc[3] / denf + b0.w, 0.f);
            o1.x = fmaxf(acc[4] / denf + b1v.x, 0.f);
            o1.y = fmaxf(acc[5] / denf + b1v.y, 0.f);
            o1.z = fmaxf(acc[6] / denf + b1v.z, 0.f);
            o1.w = fmaxf(acc[7] / denf + b1v.w, 0.f);
            *(float4*)&sh[wid][8 * c]     = o0;
            *(float4*)&sh[wid][8 * c + 4] = o1;
        }
    }
    __syncthreads();
    if (node >= n) return;
    // ---- layer-2 transform: hl = h1@W2l (fp16), hr = h1@W2r (fp32), dim = lane ----
    float accl = 0.f, accr = 0.f;
#pragma unroll 8
    for (int q = 0; q < 64; ++q) {
        float hv = sh[wid][q];
        accl += hv * W2l[q * 64 + lane];
        accr += hv * W2r[q * 64 + lane];
    }
    hl[(size_t)node * 64 + lane] = __float2half(accl);
    hr[(size_t)node * 64 + lane] = accr;
}

// ---- Layer 2 fused GATv2 + pool: same 8-group structure, full-group red8 logit.
__global__ void __launch_bounds__(256, 5)
k_gat2(const int* __restrict__ ssrc, const int* __restrict__ deg,
       const __half* __restrict__ hl, const float* __restrict__ hr,
       const float* __restrict__ att2, const float* __restrict__ b2,
       const int* __restrict__ batch,
       float* __restrict__ pooled, float* __restrict__ cnt, int n) {
    int node = __builtin_amdgcn_readfirstlane((blockIdx.x * blockDim.x + threadIdx.x) >> 6);
    if (node >= n) return;
    int lane = threadIdx.x & 63;
    int g = lane >> 3, c = lane & 7;
    float hrd[8], attv[8];
    {
        float4 v0 = *(const float4*)(hr + (size_t)node * 64 + 8 * c);
        float4 v1 = *(const float4*)(hr + (size_t)node * 64 + 8 * c + 4);
        hrd[0] = v0.x; hrd[1] = v0.y; hrd[2] = v0.z; hrd[3] = v0.w;
        hrd[4] = v1.x; hrd[5] = v1.y; hrd[6] = v1.z; hrd[7] = v1.w;
        float4 a0 = *(const float4*)(att2 + 8 * c);
        float4 a1 = *(const float4*)(att2 + 8 * c + 4);
        attv[0] = a0.x; attv[1] = a0.y; attv[2] = a0.z; attv[3] = a0.w;
        attv[4] = a1.x; attv[5] = a1.y; attv[6] = a1.z; attv[7] = a1.w;
    }
    float m = -1e30f, den = 0.f;
    float acc[8];
#pragma unroll
    for (int d = 0; d < 8; ++d) acc[d] = 0.f;
    const int* bp_ = ssrc + (size_t)node * BUCKET;
    int end = deg[node]; if (end > BUCKET) end = BUCKET;
    int idx[4];
#pragma unroll
    for (int j = 0; j < 4; ++j) { int e = 8 * j + g; idx[j] = bp_[e < end ? e : 0]; }
    for (int k = 0; k < end; k += 32) {
        float4 raw[4];
#pragma unroll
        for (int j = 0; j < 4; ++j)
            raw[j] = *(const float4*)((const char*)hl + (((size_t)(unsigned)idx[j]) << 7) + ((unsigned)c << 4));
        int kn = k + 32;
        if (kn < end) {
#pragma unroll
            for (int j = 0; j < 4; ++j) { int e = kn + 8 * j + g; idx[j] = bp_[e < end ? e : 0]; }
        }
        float av[4][8], s[4];
        bool vl[4];
#pragma unroll
        for (int j = 0; j < 4; ++j) {
            vl[j] = (k + 8 * j + g) < end;
            const __half2* hp = (const __half2*)&raw[j];
#pragma unroll
            for (int q = 0; q < 4; ++q) {
                float2 f = __half22float2(hp[q]);
                av[j][2 * q] = f.x; av[j][2 * q + 1] = f.y;
            }
            float sj = 0.f;
#pragma unroll
            for (int d = 0; d < 8; ++d) sj += lrelu(av[j][d] + hrd[d]) * attv[d];
            s[j] = red8(sj);                // full 64-dim logit (1 head)
        }
        float mb = fmaxf(fmaxf(vl[0] ? s[0] : -1e30f, vl[1] ? s[1] : -1e30f),
                         fmaxf(vl[2] ? s[2] : -1e30f, vl[3] ? s[3] : -1e30f));
        float mn = fmaxf(m, mb);
        float sc = __expf(m - mn);
        den *= sc;
#pragma unroll
        for (int d = 0; d < 8; ++d) acc[d] *= sc;
#pragma unroll
        for (int j = 0; j < 4; ++j) {
            float p = vl[j] ? __expf(s[j] - mn) : 0.f;
            den += p;
#pragma unroll
            for (int d = 0; d < 8; ++d) acc[d] += p * av[j][d];
        }
        m = mn;
    }
    // merge the 8 edge-groups
#pragma unroll
    for (int off = 8; off <= 32; off <<= 1) {
        float m_o = __shfl_xor(m, off, 64);
        float d_o = __shfl_xor(den, off, 64);
        float a_o[8];
#pragma unroll
        for (int d = 0; d < 8; ++d) a_o[d] = __shfl_xor(acc[d], off, 64);
        float mf = fmaxf(m, m_o);
        float s0 = __expf(m - mf), s1 = __expf(m_o - mf);
        den = den * s0 + d_o * s1;
#pragma unroll
        for (int d = 0; d < 8; ++d) acc[d] = acc[d] * s0 + a_o[d] * s1;
        m = mf;
    }
    float denf = den + 1e-16f;
    // ---- pool epilogue: lane (g,c) writes dim 8c+g exactly once ----
    float v = acc[0];
#pragma unroll
    for (int q = 1; q < 8; ++q) v = (g == q) ? acc[q] : v;
    float bsel = b2[8 * c + g];
    v = fmaxf(v / denf + bsel, 0.f);
    int gr = batch[node];
    atomicAdd(&pooled[(size_t)gr * 64 + 8 * c + g], v);
    if (lane == 0) atomicAdd(&cnt[gr], 1.0f);
}

// ---- Predict: out[g] = dot(pooled[g]/max(cnt,1), Wp) + bp ----
__global__ void k_predict(const float* __restrict__ pooled, const float* __restrict__ cnt,
                          const float* __restrict__ Wp, const float* __restrict__ bp,
                          float* __restrict__ out, int G) {
    int tid = blockIdx.x * blockDim.x + threadIdx.x;
    int g = tid >> 6;
    if (g >= G) return;
    int lane = threadIdx.x & 63;
    float c = cnt[g];
    if (c < 1.f) c = 1.f;
    float v = (pooled[(size_t)g * 64 + lane] / c) * Wp[lane];
#pragma unroll
    for (int off = 32; off > 0; off >>= 1) v += __shfl_down(v, off, 64);
    if (lane == 0) out[g] = v + bp[0];
}

extern "C" void kernel_launch(void* const* d_in, const int* in_sizes, int n_in,
                              void* d_out, int out_size, void* d_ws, size_t ws_size,
                              hipStream_t stream) {
    const float* x    = (const float*)d_in[0];
    const int*   ei   = (const int*)d_in[1];
    const int*   batch= (const int*)d_in[2];
    const float* W1l  = (const float*)d_in[3];
    const float* W1r  = (const float*)d_in[4];
    const float* att1 = (const float*)d_in[5];
    const float* b1   = (const float*)d_in[6];
    const float* W2l  = (const float*)d_in[7];
    const float* W2r  = (const float*)d_in[8];
    const float* att2 = (const float*)d_in[9];
    const float* b2   = (const float*)d_in[10];
    const float* Wp   = (const float*)d_in[11];
    const float* bp   = (const float*)d_in[12];
    float* out = (float*)d_out;

    const int n  = in_sizes[0] / 5;        // 50000
    const int E  = in_sizes[1] / 2;        // 1600000
    const int ET = E + n;                  // +self-loops
    const int G  = out_size;               // 512

    // ---- workspace layout ----
    char* ws = (char*)d_ws;
    size_t off = 0;
    auto alloc_b = [&](size_t bytes) { void* p = (void*)(ws + off); off += (bytes + 15) & ~15ull; return p; };
    __half* xl    = (__half*)alloc_b((size_t)n * 64 * 2);  // layer-1 gather array (fp16)
    float*  xr    = (float*)alloc_b((size_t)n * 64 * 4);
    __half* hl    = (__half*)alloc_b((size_t)n * 64 * 2);  // layer-2 gather array (fp16)
    float*  hr    = (float*)alloc_b((size_t)n * 64 * 4);
    float*  pooled= (float*)alloc_b((size_t)G * 64 * 4);   // zero region start
    float*  cntf  = (float*)alloc_b((size_t)G * 4);
    int*    deg   = (int*)alloc_b((size_t)n * 4);          // zero region end
    int*    ssrc  = (int*)alloc_b((size_t)n * BUCKET * 4); // fixed-stride buckets (19.2 MB)

    size_t zero_bytes = (size_t)((char*)deg - (char*)pooled) + (size_t)n * 4;
    (void)hipMemsetAsync(pooled, 0, zero_bytes, stream);

    const int B = 256;
    const int NSUB = 256;                  // edge-chunks per dst-partition

    // one-pass CSR build into fixed buckets (deg[] = degrees as byproduct)
    k_scatter<<<8 * NSUB, B, 0, stream>>>(ei, deg, ssrc, E, ET, n, NSUB);

    // layer-1 node transform
    k_t1<<<(n * 64 + B - 1) / B, B, 0, stream>>>(x, W1l, W1r, xl, xr, n);

    // fused GAT layer 1 + transform2  ->  hl (fp16), hr (fp32)
    k_gat1<<<(n + 3) / 4, B, 0, stream>>>(ssrc, deg, xl, xr, att1, b1, W2l, W2r, hl, hr, n);
    // fused GAT layer 2 + pool
    k_gat2<<<((size_t)n * 64 + B - 1) / B, B, 0, stream>>>(ssrc, deg, hl, hr, att2, b2, batch, pooled, cntf, n);
    // predict
    k_predict<<<(G * 64 + B - 1) / B, B, 0, stream>>>(pooled, cntf, Wp, bp, out, G);
}

// Round 3
// 345.527 us; speedup vs baseline: 1.1076x; 1.1076x over previous
//
#include <hip/hip_runtime.h>
#include <hip/hip_fp16.h>
#include <math.h>

#define NEG_SLOPE 0.2f
#define BUCKET 96            // fixed bucket stride (slots per node); P(deg>95) ~ 1e-28

__device__ __forceinline__ float lrelu(float x) { return fmaxf(x, NEG_SLOPE * x); }

// One DPP cross-lane add step (VALU pipe, no DS ops). ctrl must be compile-time.
template <int CTRL>
__device__ __forceinline__ float dpp_add(float x) {
    int t = __builtin_amdgcn_update_dpp(0, __float_as_int(x), CTRL, 0xF, 0xF, false);
    return x + __int_as_float(t);
}

// Sum over each 8-lane group (values replicated in group).
__device__ __forceinline__ float red8(float x) {
    x = dpp_add<0xB1>(x);    // quad_perm [1,0,3,2]  (xor 1)
    x = dpp_add<0x4E>(x);    // quad_perm [2,3,0,1]  (xor 2)
    x = dpp_add<0x141>(x);   // row_half_mirror      (xor 4, quads uniform)
    return x;
}

// Sum over each 32-lane half (values replicated in half).
__device__ __forceinline__ float red32(float x) {
    x = red8(x);
    x = dpp_add<0x140>(x);           // row_mirror (xor 8, 8-groups uniform)
    x += __shfl_xor(x, 16, 64);      // xor 16 (stays within each 32-half)
    return x;
}

// ---- CSR build, one pass: dst-range-partitioned direct scatter into fixed buckets.
__global__ void k_scatter(const int* __restrict__ ei, int* __restrict__ cnt,
                          int* __restrict__ ssrc, int E, int ET, int n, int nsub) {
    int part = blockIdx.x & 7;
    int sub  = blockIdx.x >> 3;
    int lo = (int)(((long long)part * n) >> 3);
    int hi = (int)(((long long)(part + 1) * n) >> 3);
    int stride = nsub * blockDim.x;
    for (int e = sub * blockDim.x + threadIdx.x; e < ET; e += stride) {
        int dst = (e < E) ? ei[E + e] : (e - E);
        if (dst >= lo && dst < hi) {
            int src = (e < E) ? ei[e] : dst;
            int pos = atomicAdd(&cnt[dst], 1);
            if (pos < BUCKET) ssrc[dst * BUCKET + pos] = src;
        }
    }
}

// ---- Layer-1 node transform: xl1 = x@W1l (fp16), xr1 = x@W1r (fp32) ----
__global__ void k_t1(const float* __restrict__ x,
                     const float* __restrict__ W1l, const float* __restrict__ W1r,
                     __half* __restrict__ xl, float* __restrict__ xr, int n) {
    __shared__ float sWl[5 * 64], sWr[5 * 64];
    int t = threadIdx.x;
    for (int i = t; i < 5 * 64; i += blockDim.x) { sWl[i] = W1l[i]; sWr[i] = W1r[i]; }
    __syncthreads();
    int tid = blockIdx.x * blockDim.x + t;
    if (tid >= n * 64) return;
    int node = tid >> 6, j = tid & 63;
    const float* xp = x + node * 5;
    float x0 = xp[0], x1 = xp[1], x2 = xp[2], x3 = xp[3], x4 = xp[4];
    float al = x0 * sWl[j] + x1 * sWl[64 + j] + x2 * sWl[128 + j] + x3 * sWl[192 + j] + x4 * sWl[256 + j];
    float ar = x0 * sWr[j] + x1 * sWr[64 + j] + x2 * sWr[128 + j] + x3 * sWr[192 + j] + x4 * sWr[256 + j];
    xl[tid] = __float2half(al);
    xr[tid] = ar;
}

// ---- Layer 1 fused GATv2 (R10 config, PROVEN — do not perturb): wave per node,
//      2 edges/wave (32 lanes x 2 dims), unrolled x8 (16 edges, 8 gathers in flight).
//      Head logit = 8-lane DPP. Epilogue: h1 -> LDS -> layer-2 transform.
__global__ void __launch_bounds__(256, 8)
k_gat1(const int* __restrict__ ssrc, const int* __restrict__ deg,
       const __half* __restrict__ xl, const float* __restrict__ xr,
       const float* __restrict__ att1, const float* __restrict__ b1,
       const float* __restrict__ W2l, const float* __restrict__ W2r,
       __half* __restrict__ hl, float* __restrict__ hr, int n) {
    __shared__ float sh[4][64];
    int t = threadIdx.x;
    int wid = t >> 6, lane = t & 63;
    int node = __builtin_amdgcn_readfirstlane(blockIdx.x * 4 + wid);
    int half = lane >> 5, l31 = lane & 31;
    if (node < n) {
        float2 xrd  = *(const float2*)(xr + (size_t)node * 64 + 2 * l31);
        float2 attv = *(const float2*)(att1 + 2 * l31);
        float m = -INFINITY, den = 0.f, acc0 = 0.f, acc1 = 0.f;
        const int* bp_ = ssrc + (size_t)node * BUCKET;    // bucket base (node uniform)
        int end = deg[node]; if (end > BUCKET) end = BUCKET;
        int k = 0;
        for (; k + 15 < end; k += 16) {                   // 16 edges: 8 gathers in flight
            float2 a[8];
#pragma unroll
            for (int j = 0; j < 8; ++j) {
                int s0 = bp_[k + 2 * j], s1 = bp_[k + 2 * j + 1];
                int sj = half ? s1 : s0;
                a[j] = __half22float2(*(const __half2*)(xl + ((unsigned)sj << 6) + 2u * l31));
            }
            float s[8];
#pragma unroll
            for (int j = 0; j < 8; ++j)
                s[j] = lrelu(a[j].x + xrd.x) * attv.x + lrelu(a[j].y + xrd.y) * attv.y;
#pragma unroll
            for (int j = 0; j < 8; ++j) s[j] = red8(s[j]);
            float mb = fmaxf(fmaxf(fmaxf(s[0], s[1]), fmaxf(s[2], s[3])),
                             fmaxf(fmaxf(s[4], s[5]), fmaxf(s[6], s[7])));
            float mn = fmaxf(m, mb);
            float sc = __expf(m - mn);
            den *= sc; acc0 *= sc; acc1 *= sc;
#pragma unroll
            for (int j = 0; j < 8; ++j) {
                float p = __expf(s[j] - mn);
                den += p; acc0 += p * a[j].x; acc1 += p * a[j].y;
            }
            m = mn;
        }
        for (; k + 7 < end; k += 8) {                     // 8-edge tier
            float2 a[4];
#pragma unroll
            for (int j = 0; j < 4; ++j) {
                int s0 = bp_[k + 2 * j], s1 = bp_[k + 2 * j + 1];
                int sj = half ? s1 : s0;
                a[j] = __half22float2(*(const __half2*)(xl + ((unsigned)sj << 6) + 2u * l31));
            }
            float s[4];
#pragma unroll
            for (int j = 0; j < 4; ++j)
                s[j] = lrelu(a[j].x + xrd.x) * attv.x + lrelu(a[j].y + xrd.y) * attv.y;
#pragma unroll
            for (int j = 0; j < 4; ++j) s[j] = red8(s[j]);
            float mb = fmaxf(fmaxf(s[0], s[1]), fmaxf(s[2], s[3]));
            float mn = fmaxf(m, mb);
            float sc = __expf(m - mn);
            den *= sc; acc0 *= sc; acc1 *= sc;
#pragma unroll
            for (int j = 0; j < 4; ++j) {
                float p = __expf(s[j] - mn);
                den += p; acc0 += p * a[j].x; acc1 += p * a[j].y;
            }
            m = mn;
        }
        for (; k + 1 < end; k += 2) {
            int s0 = bp_[k], s1 = bp_[k + 1];
            int sj = half ? s1 : s0;
            float2 a = __half22float2(*(const __half2*)(xl + ((unsigned)sj << 6) + 2u * l31));
            float s = lrelu(a.x + xrd.x) * attv.x + lrelu(a.y + xrd.y) * attv.y;
            s = red8(s);
            float mn = fmaxf(m, s);
            float sc = __expf(m - mn);
            float p  = __expf(s - mn);
            den = den * sc + p;
            acc0 = acc0 * sc + p * a.x;
            acc1 = acc1 * sc + p * a.y;
            m = mn;
        }
        if (k < end) {                                    // odd tail: lo half only
            int sj = bp_[k];
            float2 a = __half22float2(*(const __half2*)(xl + ((unsigned)sj << 6) + 2u * l31));
            float s = lrelu(a.x + xrd.x) * attv.x + lrelu(a.y + xrd.y) * attv.y;
            s = red8(s);
            if (half == 0) {
                float mn = fmaxf(m, s);
                float sc = __expf(m - mn);
                float p  = __expf(s - mn);
                den = den * sc + p;
                acc0 = acc0 * sc + p * a.x;
                acc1 = acc1 * sc + p * a.y;
                m = mn;
            }
        }
        // merge halves (lo half has >=1 edge so no double -inf)
        float m_o  = __shfl_xor(m, 32, 64);
        float d_o  = __shfl_xor(den, 32, 64);
        float a0_o = __shfl_xor(acc0, 32, 64);
        float a1_o = __shfl_xor(acc1, 32, 64);
        float mf = fmaxf(m, m_o);
        float sc = __expf(m - mf), sco = __expf(m_o - mf);
        float denf = den * sc + d_o * sco + 1e-16f;
        float2 b = *(const float2*)(b1 + 2 * l31);
        float o0 = fmaxf((acc0 * sc + a0_o * sco) / denf + b.x, 0.f);
        float o1 = fmaxf((acc1 * sc + a1_o * sco) / denf + b.y, 0.f);
        if (half == 0) *(float2*)&sh[wid][2 * l31] = make_float2(o0, o1);
    }
    __syncthreads();
    if (node >= n) return;
    // ---- layer-2 transform: hl = h1@W2l (fp16), hr = h1@W2r (fp32), dim = lane ----
    float accl = 0.f, accr = 0.f;
#pragma unroll 8
    for (int q = 0; q < 64; ++q) {
        float hv = sh[wid][q];
        accl += hv * W2l[q * 64 + lane];
        accr += hv * W2r[q * 64 + lane];
    }
    hl[(size_t)node * 64 + lane] = __float2half(accl);
    hr[(size_t)node * 64 + lane] = accr;
}

// ---- k_gat2 helpers: R10 round internals, factored so two nodes can interleave ----

// Load 16 edges' features (2 edges per 32-lane half slot, 8 gathers/lane).
__device__ __forceinline__ void load16(const int* __restrict__ bp_, int k,
                                       const __half* __restrict__ hl,
                                       int half, int l31, float2* a) {
#pragma unroll
    for (int j = 0; j < 8; ++j) {
        int s0 = bp_[k + 2 * j], s1 = bp_[k + 2 * j + 1];
        int sj = half ? s1 : s0;
        a[j] = __half22float2(*(const __half2*)(hl + ((unsigned)sj << 6) + 2u * l31));
    }
}

// Online-softmax update for a 16-edge block (R10 math, red32 logits).
__device__ __forceinline__ void upd16(const float2* a, float2 hrd, float2 attv,
                                      float& m, float& den, float& acc0, float& acc1) {
    float s[8];
#pragma unroll
    for (int j = 0; j < 8; ++j)
        s[j] = lrelu(a[j].x + hrd.x) * attv.x + lrelu(a[j].y + hrd.y) * attv.y;
#pragma unroll
    for (int j = 0; j < 8; ++j) s[j] = red32(s[j]);
    float mb = fmaxf(fmaxf(fmaxf(s[0], s[1]), fmaxf(s[2], s[3])),
                     fmaxf(fmaxf(s[4], s[5]), fmaxf(s[6], s[7])));
    float mn = fmaxf(m, mb);
    float sc = __expf(m - mn);
    den *= sc; acc0 *= sc; acc1 *= sc;
#pragma unroll
    for (int j = 0; j < 8; ++j) {
        float p = __expf(s[j] - mn);
        den += p; acc0 += p * a[j].x; acc1 += p * a[j].y;
    }
    m = mn;
}

// Finish one node's remaining edges from k: exact R10 tier chain (16/8/2/1).
__device__ __forceinline__ void gat2_tail(const int* __restrict__ bp_, int k, int end,
                                          const __half* __restrict__ hl,
                                          float2 hrd, float2 attv, int half, int l31,
                                          float& m, float& den, float& acc0, float& acc1) {
    for (; k + 15 < end; k += 16) {
        float2 a[8];
        load16(bp_, k, hl, half, l31, a);
        upd16(a, hrd, attv, m, den, acc0, acc1);
    }
    for (; k + 7 < end; k += 8) {
        float2 a[4];
#pragma unroll
        for (int j = 0; j < 4; ++j) {
            int s0 = bp_[k + 2 * j], s1 = bp_[k + 2 * j + 1];
            int sj = half ? s1 : s0;
            a[j] = __half22float2(*(const __half2*)(hl + ((unsigned)sj << 6) + 2u * l31));
        }
        float s[4];
#pragma unroll
        for (int j = 0; j < 4; ++j)
            s[j] = lrelu(a[j].x + hrd.x) * attv.x + lrelu(a[j].y + hrd.y) * attv.y;
#pragma unroll
        for (int j = 0; j < 4; ++j) s[j] = red32(s[j]);
        float mb = fmaxf(fmaxf(s[0], s[1]), fmaxf(s[2], s[3]));
        float mn = fmaxf(m, mb);
        float sc = __expf(m - mn);
        den *= sc; acc0 *= sc; acc1 *= sc;
#pragma unroll
        for (int j = 0; j < 4; ++j) {
            float p = __expf(s[j] - mn);
            den += p; acc0 += p * a[j].x; acc1 += p * a[j].y;
        }
        m = mn;
    }
    for (; k + 1 < end; k += 2) {
        int s0 = bp_[k], s1 = bp_[k + 1];
        int sj = half ? s1 : s0;
        float2 a = __half22float2(*(const __half2*)(hl + ((unsigned)sj << 6) + 2u * l31));
        float s = lrelu(a.x + hrd.x) * attv.x + lrelu(a.y + hrd.y) * attv.y;
        s = red32(s);
        float mn = fmaxf(m, s);
        float sc = __expf(m - mn);
        float p  = __expf(s - mn);
        den = den * sc + p;
        acc0 = acc0 * sc + p * a.x;
        acc1 = acc1 * sc + p * a.y;
        m = mn;
    }
    if (k < end) {                                        // odd tail: lo half only
        int sj = bp_[k];
        float2 a = __half22float2(*(const __half2*)(hl + ((unsigned)sj << 6) + 2u * l31));
        float s = lrelu(a.x + hrd.x) * attv.x + lrelu(a.y + hrd.y) * attv.y;
        s = red32(s);
        if (half == 0) {
            float mn = fmaxf(m, s);
            float sc = __expf(m - mn);
            float p  = __expf(s - mn);
            den = den * sc + p;
            acc0 = acc0 * sc + p * a.x;
            acc1 = acc1 * sc + p * a.y;
            m = mn;
        }
    }
}

// Half-merge + softmax normalize + pooled atomics for one node (R10 epilogue).
__device__ __forceinline__ void gat2_finish(float m, float den, float acc0, float acc1,
                                            const float* __restrict__ b2,
                                            const int* __restrict__ batch, int node,
                                            float* __restrict__ pooled, float* __restrict__ cnt,
                                            int lane, int half, int l31) {
    float m_o  = __shfl_xor(m, 32, 64);
    float d_o  = __shfl_xor(den, 32, 64);
    float a0_o = __shfl_xor(acc0, 32, 64);
    float a1_o = __shfl_xor(acc1, 32, 64);
    float mf = fmaxf(m, m_o);
    float sc = __expf(m - mf), sco = __expf(m_o - mf);
    float denf = den * sc + d_o * sco + 1e-16f;
    float2 b = *(const float2*)(b2 + 2 * l31);
    float o0 = fmaxf((acc0 * sc + a0_o * sco) / denf + b.x, 0.f);
    float o1 = fmaxf((acc1 * sc + a1_o * sco) / denf + b.y, 0.f);
    int gr = batch[node];
    atomicAdd(&pooled[(size_t)gr * 64 + 2 * l31 + half], half ? o1 : o0);
    if (lane == 0) atomicAdd(&cnt[gr], 1.0f);
}

// ---- Layer 2 fused GATv2 + pool (R16): TWO adjacent nodes per wave, rounds
//      interleaved (issue A gathers, issue B gathers -> 16 in flight, compute A,
//      compute B). Per-node round internals identical to proven R10; tails use
//      the exact R10 tier chain. Doubles per-wave MLP without perturbing the loop.
__global__ void __launch_bounds__(256, 6)
k_gat2(const int* __restrict__ ssrc, const int* __restrict__ deg,
       const __half* __restrict__ hl, const float* __restrict__ hr,
       const float* __restrict__ att2, const float* __restrict__ b2,
       const int* __restrict__ batch,
       float* __restrict__ pooled, float* __restrict__ cnt, int n) {
    int wave = __builtin_amdgcn_readfirstlane((blockIdx.x * blockDim.x + threadIdx.x) >> 6);
    int nA = wave * 2;
    if (nA >= n) return;
    int nB = nA + 1;
    bool hasB = (nB < n);
    int lane = threadIdx.x & 63;
    int half = lane >> 5, l31 = lane & 31;
    float2 attv = *(const float2*)(att2 + 2 * l31);
    float2 hrdA = *(const float2*)(hr + (size_t)nA * 64 + 2 * l31);
    float2 hrdB = hasB ? *(const float2*)(hr + (size_t)nB * 64 + 2 * l31) : make_float2(0.f, 0.f);
    const int* bpA = ssrc + (size_t)nA * BUCKET;
    const int* bpB = ssrc + (size_t)nB * BUCKET;
    int endA = deg[nA]; if (endA > BUCKET) endA = BUCKET;
    int endB = hasB ? deg[nB] : 0; if (endB > BUCKET) endB = BUCKET;
    float mA = -INFINITY, denA = 0.f, a0A = 0.f, a1A = 0.f;
    float mB = -INFINITY, denB = 0.f, a0B = 0.f, a1B = 0.f;
    int endmin = endA < endB ? endA : endB;
    int k = 0;
    for (; k + 15 < endmin; k += 16) {       // interleaved: 32 edges, 16 gathers in flight
        float2 aA[8], aB[8];
        load16(bpA, k, hl, half, l31, aA);
        load16(bpB, k, hl, half, l31, aB);
        upd16(aA, hrdA, attv, mA, denA, a0A, a1A);
        upd16(aB, hrdB, attv, mB, denB, a0B, a1B);
    }
    // per-node remainders: exact R10 tier chain (same edge order as R10)
    gat2_tail(bpA, k, endA, hl, hrdA, attv, half, l31, mA, denA, a0A, a1A);
    if (hasB) gat2_tail(bpB, k, endB, hl, hrdB, attv, half, l31, mB, denB, a0B, a1B);
    gat2_finish(mA, denA, a0A, a1A, b2, batch, nA, pooled, cnt, lane, half, l31);
    if (hasB) gat2_finish(mB, denB, a0B, a1B, b2, batch, nB, pooled, cnt, lane, half, l31);
}

// ---- Predict: out[g] = dot(pooled[g]/max(cnt,1), Wp) + bp ----
__global__ void k_predict(const float* __restrict__ pooled, const float* __restrict__ cnt,
                          const float* __restrict__ Wp, const float* __restrict__ bp,
                          float* __restrict__ out, int G) {
    int tid = blockIdx.x * blockDim.x + threadIdx.x;
    int g = tid >> 6;
    if (g >= G) return;
    int lane = threadIdx.x & 63;
    float c = cnt[g];
    if (c < 1.f) c = 1.f;
    float v = (pooled[(size_t)g * 64 + lane] / c) * Wp[lane];
#pragma unroll
    for (int off = 32; off > 0; off >>= 1) v += __shfl_down(v, off, 64);
    if (lane == 0) out[g] = v + bp[0];
}

extern "C" void kernel_launch(void* const* d_in, const int* in_sizes, int n_in,
                              void* d_out, int out_size, void* d_ws, size_t ws_size,
                              hipStream_t stream) {
    const float* x    = (const float*)d_in[0];
    const int*   ei   = (const int*)d_in[1];
    const int*   batch= (const int*)d_in[2];
    const float* W1l  = (const float*)d_in[3];
    const float* W1r  = (const float*)d_in[4];
    const float* att1 = (const float*)d_in[5];
    const float* b1   = (const float*)d_in[6];
    const float* W2l  = (const float*)d_in[7];
    const float* W2r  = (const float*)d_in[8];
    const float* att2 = (const float*)d_in[9];
    const float* b2   = (const float*)d_in[10];
    const float* Wp   = (const float*)d_in[11];
    const float* bp   = (const float*)d_in[12];
    float* out = (float*)d_out;

    const int n  = in_sizes[0] / 5;        // 50000
    const int E  = in_sizes[1] / 2;        // 1600000
    const int ET = E + n;                  // +self-loops
    const int G  = out_size;               // 512

    // ---- workspace layout ----
    char* ws = (char*)d_ws;
    size_t off = 0;
    auto alloc_b = [&](size_t bytes) { void* p = (void*)(ws + off); off += (bytes + 15) & ~15ull; return p; };
    __half* xl    = (__half*)alloc_b((size_t)n * 64 * 2);  // layer-1 gather array (fp16)
    float*  xr    = (float*)alloc_b((size_t)n * 64 * 4);
    __half* hl    = (__half*)alloc_b((size_t)n * 64 * 2);  // layer-2 gather array (fp16)
    float*  hr    = (float*)alloc_b((size_t)n * 64 * 4);
    float*  pooled= (float*)alloc_b((size_t)G * 64 * 4);   // zero region start
    float*  cntf  = (float*)alloc_b((size_t)G * 4);
    int*    deg   = (int*)alloc_b((size_t)n * 4);          // zero region end
    int*    ssrc  = (int*)alloc_b((size_t)n * BUCKET * 4); // fixed-stride buckets (19.2 MB)

    size_t zero_bytes = (size_t)((char*)deg - (char*)pooled) + (size_t)n * 4;
    (void)hipMemsetAsync(pooled, 0, zero_bytes, stream);

    const int B = 256;
    const int NSUB = 256;                  // edge-chunks per dst-partition

    // one-pass CSR build into fixed buckets (deg[] = degrees as byproduct)
    k_scatter<<<8 * NSUB, B, 0, stream>>>(ei, deg, ssrc, E, ET, n, NSUB);

    // layer-1 node transform
    k_t1<<<(n * 64 + B - 1) / B, B, 0, stream>>>(x, W1l, W1r, xl, xr, n);

    // fused GAT layer 1 + transform2  ->  hl (fp16), hr (fp32)
    k_gat1<<<(n + 3) / 4, B, 0, stream>>>(ssrc, deg, xl, xr, att1, b1, W2l, W2r, hl, hr, n);
    // fused GAT layer 2 + pool: two nodes per wave
    {
        int nwaves = (n + 1) / 2;
        k_gat2<<<(nwaves + 3) / 4, B, 0, stream>>>(ssrc, deg, hl, hr, att2, b2, batch, pooled, cntf, n);
    }
    // predict
    k_predict<<<(G * 64 + B - 1) / B, B, 0, stream>>>(pooled, cntf, Wp, bp, out, G);
}